// Round 1
// baseline (485.393 us; speedup 1.0000x reference)
//
#include <hip/hip_runtime.h>
#include <math.h>

#define N_NODES 50000
#define N_EDGES 800000
#define NFEAT 256
#define NHID 64
#define NCLASS 2

// ---------------- workspace layout (floats) ----------------
// [0)        norm_src   50048   (deg accumulated here, then rsqrt in place)
// [50048)    norm_dst   50048
// [100096)   agg1       3200000 (then relu'd h1 in place)
// [3300096)  agg2       100096
// [3400192)  h          3200000
// [6600192)  h2         100000
// zero range: [0, 3400192)
#define OFF_NSRC 0
#define OFF_NDST 50048
#define OFF_AGG1 100096
#define OFF_AGG2 3300096
#define OFF_H    3400192
#define OFF_H2   6600192
#define ZERO_FLOATS 3400192

__global__ void zero_kernel(float4* __restrict__ p, int n4) {
    int i = blockIdx.x * blockDim.x + threadIdx.x;
    if (i < n4) p[i] = make_float4(0.f, 0.f, 0.f, 0.f);
}

__global__ void deg_kernel(const int* __restrict__ src, const int* __restrict__ dst,
                           float* __restrict__ deg_src, float* __restrict__ deg_dst) {
    int e = blockIdx.x * blockDim.x + threadIdx.x;
    if (e < N_EDGES) {
        atomicAdd(&deg_src[src[e]], 1.0f);
        atomicAdd(&deg_dst[dst[e]], 1.0f);
    }
}

__global__ void norm_kernel(float* __restrict__ v, int n) {
    int i = blockIdx.x * blockDim.x + threadIdx.x;
    if (i < n) v[i] = rsqrtf(fmaxf(v[i], 1.0f));
}

// h[50000x64] = (x * norm_src[:,None]) @ W1[256x64]
// 64-row x 64-col tile per 256-thread block, K chunks of 16.
#define BM 64
#define BK 16
__global__ __launch_bounds__(256) void gemm1_kernel(const float* __restrict__ x,
                                                    const float* __restrict__ W1,
                                                    const float* __restrict__ norm_src,
                                                    float* __restrict__ h) {
    __shared__ float As[BK][BM + 4];    // As[kk][r], stride 68 floats (16B-aligned)
    __shared__ float Bs[BK][NHID + 4];  // Bs[kk][c]
    const int row0 = blockIdx.x * BM;
    const int t = threadIdx.x;
    const int tx = t & 15;        // col group (4 cols)
    const int ty = t >> 4;        // row group (4 rows)
    // A staging: thread -> (row ar, k-quad ak)
    const int ar = t >> 2;        // 0..63
    const int ak = (t & 3) * 4;   // 0,4,8,12
    // B staging: thread -> (k bk, col-quad bc)
    const int bk = t >> 4;        // 0..15
    const int bc = (t & 15) * 4;  // 0..60
    const int grow = row0 + ar;
    const float anorm = (grow < N_NODES) ? norm_src[grow] : 0.0f;

    float acc[4][4] = {};
    for (int k0 = 0; k0 < NFEAT; k0 += BK) {
        float4 av = make_float4(0.f, 0.f, 0.f, 0.f);
        if (grow < N_NODES) av = *(const float4*)(&x[grow * NFEAT + k0 + ak]);
        As[ak + 0][ar] = av.x * anorm;
        As[ak + 1][ar] = av.y * anorm;
        As[ak + 2][ar] = av.z * anorm;
        As[ak + 3][ar] = av.w * anorm;
        *(float4*)(&Bs[bk][bc]) = *(const float4*)(&W1[(k0 + bk) * NHID + bc]);
        __syncthreads();
#pragma unroll
        for (int kk = 0; kk < BK; ++kk) {
            float4 a4 = *(const float4*)(&As[kk][ty * 4]);
            float4 b4 = *(const float4*)(&Bs[kk][tx * 4]);
            float a[4] = {a4.x, a4.y, a4.z, a4.w};
            float b[4] = {b4.x, b4.y, b4.z, b4.w};
#pragma unroll
            for (int i = 0; i < 4; ++i)
#pragma unroll
                for (int j = 0; j < 4; ++j)
                    acc[i][j] = fmaf(a[i], b[j], acc[i][j]);
        }
        __syncthreads();
    }
#pragma unroll
    for (int i = 0; i < 4; ++i) {
        int r = row0 + ty * 4 + i;
        if (r < N_NODES) {
            float4 o = make_float4(acc[i][0], acc[i][1], acc[i][2], acc[i][3]);
            *(float4*)(&h[r * NHID + tx * 4]) = o;
        }
    }
}

// agg1[dst] += h[src], 64 feats: one wave per edge, lane = feature
__global__ void agg1_kernel(const int* __restrict__ src, const int* __restrict__ dst,
                            const float* __restrict__ h, float* __restrict__ agg) {
    int gtid = blockIdx.x * blockDim.x + threadIdx.x;
    int e = gtid >> 6;
    int lane = gtid & 63;
    if (e < N_EDGES) {
        int s = src[e], d = dst[e];
        float v = h[s * 64 + lane];
        atomicAdd(&agg[d * 64 + lane], v);
    }
}

// h1 = relu(agg1 * norm_dst + b1), in place
__global__ void epi1_kernel(float* __restrict__ agg, const float* __restrict__ norm_dst,
                            const float* __restrict__ b1) {
    int i = blockIdx.x * blockDim.x + threadIdx.x;
    if (i < N_NODES * NHID) {
        int n = i >> 6, f = i & 63;
        float v = fmaf(agg[i], norm_dst[n], b1[f]);
        agg[i] = fmaxf(v, 0.0f);
    }
}

// h2[50000x2] = (h1 * norm_src[:,None]) @ W2[64x2] ; one wave per node
__global__ void gemm2_kernel(const float* __restrict__ h1, const float* __restrict__ W2,
                             const float* __restrict__ norm_src, float* __restrict__ h2) {
    int gtid = blockIdx.x * blockDim.x + threadIdx.x;
    int node = gtid >> 6;
    int lane = gtid & 63;
    if (node < N_NODES) {
        float v = h1[node * NHID + lane] * norm_src[node];
        float p0 = v * W2[lane * 2 + 0];
        float p1 = v * W2[lane * 2 + 1];
#pragma unroll
        for (int off = 32; off > 0; off >>= 1) {
            p0 += __shfl_down(p0, off, 64);
            p1 += __shfl_down(p1, off, 64);
        }
        if (lane == 0) {
            h2[node * 2 + 0] = p0;
            h2[node * 2 + 1] = p1;
        }
    }
}

// agg2[dst] += h2[src], 2 feats: one thread per edge
__global__ void agg2_kernel(const int* __restrict__ src, const int* __restrict__ dst,
                            const float* __restrict__ h2, float* __restrict__ agg2) {
    int e = blockIdx.x * blockDim.x + threadIdx.x;
    if (e < N_EDGES) {
        int s = src[e], d = dst[e];
        float2 v = *(const float2*)(&h2[s * 2]);
        atomicAdd(&agg2[d * 2 + 0], v.x);
        atomicAdd(&agg2[d * 2 + 1], v.y);
    }
}

// out = log_softmax(agg2 * norm_dst + b2)
__global__ void final_kernel(const float* __restrict__ agg2, const float* __restrict__ norm_dst,
                             const float* __restrict__ b2, float* __restrict__ out) {
    int n = blockIdx.x * blockDim.x + threadIdx.x;
    if (n < N_NODES) {
        float nd = norm_dst[n];
        float l0 = fmaf(agg2[n * 2 + 0], nd, b2[0]);
        float l1 = fmaf(agg2[n * 2 + 1], nd, b2[1]);
        float m = fmaxf(l0, l1);
        float lse = m + logf(expf(l0 - m) + expf(l1 - m));
        out[n * 2 + 0] = l0 - lse;
        out[n * 2 + 1] = l1 - lse;
    }
}

extern "C" void kernel_launch(void* const* d_in, const int* in_sizes, int n_in,
                              void* d_out, int out_size, void* d_ws, size_t ws_size,
                              hipStream_t stream) {
    const float* x  = (const float*)d_in[0];
    const int* src  = (const int*)d_in[1];
    const int* dst  = (const int*)d_in[2];
    const float* W1 = (const float*)d_in[3];
    const float* b1 = (const float*)d_in[4];
    const float* W2 = (const float*)d_in[5];
    const float* b2 = (const float*)d_in[6];
    float* out = (float*)d_out;
    float* ws  = (float*)d_ws;

    float* norm_src = ws + OFF_NSRC;
    float* norm_dst = ws + OFF_NDST;
    float* agg1     = ws + OFF_AGG1;
    float* agg2     = ws + OFF_AGG2;
    float* h        = ws + OFF_H;
    float* h2       = ws + OFF_H2;

    // zero degree + aggregation buffers (ws is poisoned before every call)
    {
        int n4 = ZERO_FLOATS / 4;
        zero_kernel<<<(n4 + 255) / 256, 256, 0, stream>>>((float4*)ws, n4);
    }
    deg_kernel<<<(N_EDGES + 255) / 256, 256, 0, stream>>>(src, dst, norm_src, norm_dst);
    norm_kernel<<<(OFF_AGG1 + 255) / 256, 256, 0, stream>>>(ws, OFF_AGG1);
    gemm1_kernel<<<(N_NODES + BM - 1) / BM, 256, 0, stream>>>(x, W1, norm_src, h);
    {
        long long threads = (long long)N_EDGES * 64;
        agg1_kernel<<<(int)((threads + 255) / 256), 256, 0, stream>>>(src, dst, h, agg1);
    }
    epi1_kernel<<<(N_NODES * NHID + 255) / 256, 256, 0, stream>>>(agg1, norm_dst, b1);
    {
        long long threads = (long long)N_NODES * 64;
        gemm2_kernel<<<(int)((threads + 255) / 256), 256, 0, stream>>>(agg1, W2, norm_src, h2);
    }
    agg2_kernel<<<(N_EDGES + 255) / 256, 256, 0, stream>>>(src, dst, h2, agg2);
    final_kernel<<<(N_NODES + 255) / 256, 256, 0, stream>>>(agg2, norm_dst, b2, out);
}

// Round 2
// 315.117 us; speedup vs baseline: 1.5404x; 1.5404x over previous
//
#include <hip/hip_runtime.h>
#include <math.h>

#define N_NODES 50000
#define N_EDGES 800000
#define NFEAT 256
#define NHID 64
#define NCLASS 2

// ---------------- workspace layout (4-byte units) ----------------
#define OFF_DEGS   0        // int[50048]  out-degree (src)
#define OFF_DEGD   50048    // int[50048]  in-degree (dst)
#define OFF_NSRC   100096   // f32[50048]  rsqrt norm of out-degree
#define OFF_NDST   150144   // f32[50048]  rsqrt norm of in-degree
#define OFF_RP     200192   // int[50048]  CSR row_ptr (by dst), needs N_NODES+1
#define OFF_NEXT   250240   // int[50048]  fill cursors
#define OFF_BSUM   300288   // int[256]    scan block sums
#define OFF_CSR    300544   // int[800000] src indices sorted by dst
#define OFF_H      1100544  // f32[3200000] h = (x*norm_src)@W1
#define OFF_H2     4300544  // f32[100000]  layer-1 output (50000 x 2)
#define ZERO_FLOATS 100096  // just the two degree arrays

__global__ void zero_kernel(float4* __restrict__ p, int n4) {
    int i = blockIdx.x * blockDim.x + threadIdx.x;
    if (i < n4) p[i] = make_float4(0.f, 0.f, 0.f, 0.f);
}

__global__ void deg_kernel(const int* __restrict__ src, const int* __restrict__ dst,
                           int* __restrict__ deg_src, int* __restrict__ deg_dst) {
    int e = blockIdx.x * blockDim.x + threadIdx.x;
    if (e < N_EDGES) {
        atomicAdd(&deg_src[src[e]], 1);
        atomicAdd(&deg_dst[dst[e]], 1);
    }
}

// norms for both arrays in one pass: i in [0, 2*50048)
__global__ void norm_kernel(const int* __restrict__ deg, float* __restrict__ norm) {
    int i = blockIdx.x * blockDim.x + threadIdx.x;
    if (i < 2 * 50048) norm[i] = rsqrtf(fmaxf((float)deg[i], 1.0f));
}

// ---- two-level exclusive scan of in-degrees -> row_ptr ----
__global__ void scan1_kernel(const int* __restrict__ deg_dst, int* __restrict__ row_ptr,
                             int* __restrict__ bsum) {
    __shared__ int s[256];
    int t = threadIdx.x;
    int i = blockIdx.x * 256 + t;
    int val = (i < N_NODES) ? deg_dst[i] : 0;
    s[t] = val;
    __syncthreads();
#pragma unroll
    for (int off = 1; off < 256; off <<= 1) {
        int x = (t >= off) ? s[t - off] : 0;
        __syncthreads();
        s[t] += x;
        __syncthreads();
    }
    if (i < N_NODES) row_ptr[i] = s[t] - val;  // exclusive within block
    if (t == 255) bsum[blockIdx.x] = s[255];
}

__global__ void scan2_kernel(int* __restrict__ bsum, int nblocks) {
    if (threadIdx.x == 0 && blockIdx.x == 0) {
        int acc = 0;
        for (int b = 0; b < nblocks; ++b) {
            int t = bsum[b];
            bsum[b] = acc;
            acc += t;
        }
    }
}

__global__ void scan3_kernel(int* __restrict__ row_ptr, const int* __restrict__ bsum,
                             int* __restrict__ next) {
    int i = blockIdx.x * blockDim.x + threadIdx.x;
    if (i < N_NODES) {
        int rp = row_ptr[i] + bsum[i >> 8];
        row_ptr[i] = rp;
        next[i] = rp;
    }
    if (i == 0) row_ptr[N_NODES] = N_EDGES;
}

__global__ void fill_kernel(const int* __restrict__ src, const int* __restrict__ dst,
                            int* __restrict__ next, int* __restrict__ csr_src) {
    int e = blockIdx.x * blockDim.x + threadIdx.x;
    if (e < N_EDGES) {
        int pos = atomicAdd(&next[dst[e]], 1);
        csr_src[pos] = src[e];
    }
}

// h[50000x64] = (x * norm_src[:,None]) @ W1[256x64]
#define BM 64
#define BK 16
__global__ __launch_bounds__(256) void gemm1_kernel(const float* __restrict__ x,
                                                    const float* __restrict__ W1,
                                                    const float* __restrict__ norm_src,
                                                    float* __restrict__ h) {
    __shared__ float As[BK][BM + 4];
    __shared__ float Bs[BK][NHID + 4];
    const int row0 = blockIdx.x * BM;
    const int t = threadIdx.x;
    const int tx = t & 15;
    const int ty = t >> 4;
    const int ar = t >> 2;
    const int ak = (t & 3) * 4;
    const int bk = t >> 4;
    const int bc = (t & 15) * 4;
    const int grow = row0 + ar;
    const float anorm = (grow < N_NODES) ? norm_src[grow] : 0.0f;

    float acc[4][4] = {};
    for (int k0 = 0; k0 < NFEAT; k0 += BK) {
        float4 av = make_float4(0.f, 0.f, 0.f, 0.f);
        if (grow < N_NODES) av = *(const float4*)(&x[grow * NFEAT + k0 + ak]);
        As[ak + 0][ar] = av.x * anorm;
        As[ak + 1][ar] = av.y * anorm;
        As[ak + 2][ar] = av.z * anorm;
        As[ak + 3][ar] = av.w * anorm;
        *(float4*)(&Bs[bk][bc]) = *(const float4*)(&W1[(k0 + bk) * NHID + bc]);
        __syncthreads();
#pragma unroll
        for (int kk = 0; kk < BK; ++kk) {
            float4 a4 = *(const float4*)(&As[kk][ty * 4]);
            float4 b4 = *(const float4*)(&Bs[kk][tx * 4]);
            float a[4] = {a4.x, a4.y, a4.z, a4.w};
            float b[4] = {b4.x, b4.y, b4.z, b4.w};
#pragma unroll
            for (int i = 0; i < 4; ++i)
#pragma unroll
                for (int j = 0; j < 4; ++j)
                    acc[i][j] = fmaf(a[i], b[j], acc[i][j]);
        }
        __syncthreads();
    }
#pragma unroll
    for (int i = 0; i < 4; ++i) {
        int r = row0 + ty * 4 + i;
        if (r < N_NODES) {
            float4 o = make_float4(acc[i][0], acc[i][1], acc[i][2], acc[i][3]);
            *(float4*)(&h[r * NHID + tx * 4]) = o;
        }
    }
}

// Fused layer1: per dst node (one wave, lane = feature):
//   agg = sum_{j in CSR[n]} h[csr_src[j]][lane]
//   h1  = relu(agg * norm_dst[n] + b1[lane])
//   hv  = h1 * norm_src[n]          (layer-2 pre-norm)
//   h2[n][c] = sum_lane hv * W2[lane][c]
__global__ void fused1_kernel(const int* __restrict__ row_ptr, const int* __restrict__ csr_src,
                              const float* __restrict__ h, const float* __restrict__ norm_dst,
                              const float* __restrict__ norm_src, const float* __restrict__ b1,
                              const float* __restrict__ W2, float* __restrict__ h2) {
    int gtid = blockIdx.x * blockDim.x + threadIdx.x;
    int node = gtid >> 6;
    int lane = gtid & 63;
    if (node >= N_NODES) return;
    int beg = row_ptr[node], end = row_ptr[node + 1];
    float acc0 = 0.f, acc1 = 0.f;
    int j = beg;
    for (; j + 1 < end; j += 2) {
        int s0 = csr_src[j], s1 = csr_src[j + 1];
        acc0 += h[s0 * 64 + lane];
        acc1 += h[s1 * 64 + lane];
    }
    if (j < end) acc0 += h[csr_src[j] * 64 + lane];
    float agg = acc0 + acc1;
    float h1 = fmaxf(fmaf(agg, norm_dst[node], b1[lane]), 0.0f);
    float hv = h1 * norm_src[node];
    float p0 = hv * W2[lane * 2 + 0];
    float p1 = hv * W2[lane * 2 + 1];
#pragma unroll
    for (int off = 32; off > 0; off >>= 1) {
        p0 += __shfl_xor(p0, off, 64);
        p1 += __shfl_xor(p1, off, 64);
    }
    if (lane == 0) *(float2*)(&h2[node * 2]) = make_float2(p0, p1);
}

// Fused layer2: per dst node (one thread):
//   s = sum h2[csr_src[j]]; logits = s*norm_dst + b2; out = log_softmax(logits)
__global__ void fused2_kernel(const int* __restrict__ row_ptr, const int* __restrict__ csr_src,
                              const float* __restrict__ h2, const float* __restrict__ norm_dst,
                              const float* __restrict__ b2, float* __restrict__ out) {
    int n = blockIdx.x * blockDim.x + threadIdx.x;
    if (n >= N_NODES) return;
    int beg = row_ptr[n], end = row_ptr[n + 1];
    float s0 = 0.f, s1 = 0.f;
    for (int j = beg; j < end; ++j) {
        float2 v = *(const float2*)(&h2[csr_src[j] * 2]);
        s0 += v.x;
        s1 += v.y;
    }
    float nd = norm_dst[n];
    float l0 = fmaf(s0, nd, b2[0]);
    float l1 = fmaf(s1, nd, b2[1]);
    float m = fmaxf(l0, l1);
    float lse = m + logf(expf(l0 - m) + expf(l1 - m));
    *(float2*)(&out[n * 2]) = make_float2(l0 - lse, l1 - lse);
}

extern "C" void kernel_launch(void* const* d_in, const int* in_sizes, int n_in,
                              void* d_out, int out_size, void* d_ws, size_t ws_size,
                              hipStream_t stream) {
    const float* x  = (const float*)d_in[0];
    const int* src  = (const int*)d_in[1];
    const int* dst  = (const int*)d_in[2];
    const float* W1 = (const float*)d_in[3];
    const float* b1 = (const float*)d_in[4];
    const float* W2 = (const float*)d_in[5];
    const float* b2 = (const float*)d_in[6];
    float* out = (float*)d_out;
    float* ws  = (float*)d_ws;
    int*   wsi = (int*)d_ws;

    int*   deg_src  = wsi + OFF_DEGS;
    int*   deg_dst  = wsi + OFF_DEGD;
    float* norm_src = ws + OFF_NSRC;
    float* norm_dst = ws + OFF_NDST;
    int*   row_ptr  = wsi + OFF_RP;
    int*   nextp    = wsi + OFF_NEXT;
    int*   bsum     = wsi + OFF_BSUM;
    int*   csr_src  = wsi + OFF_CSR;
    float* h        = ws + OFF_H;
    float* h2       = ws + OFF_H2;

    const int NB_SCAN = (N_NODES + 255) / 256;  // 196

    zero_kernel<<<(ZERO_FLOATS / 4 + 255) / 256, 256, 0, stream>>>((float4*)ws, ZERO_FLOATS / 4);
    deg_kernel<<<(N_EDGES + 255) / 256, 256, 0, stream>>>(src, dst, deg_src, deg_dst);
    norm_kernel<<<(2 * 50048 + 255) / 256, 256, 0, stream>>>(deg_src, norm_src);
    scan1_kernel<<<NB_SCAN, 256, 0, stream>>>(deg_dst, row_ptr, bsum);
    scan2_kernel<<<1, 64, 0, stream>>>(bsum, NB_SCAN);
    scan3_kernel<<<NB_SCAN, 256, 0, stream>>>(row_ptr, bsum, nextp);
    fill_kernel<<<(N_EDGES + 255) / 256, 256, 0, stream>>>(src, dst, nextp, csr_src);
    gemm1_kernel<<<(N_NODES + BM - 1) / BM, 256, 0, stream>>>(x, W1, norm_src, h);
    {
        long long threads = (long long)N_NODES * 64;
        fused1_kernel<<<(int)((threads + 255) / 256), 256, 0, stream>>>(
            row_ptr, csr_src, h, norm_dst, norm_src, b1, W2, h2);
    }
    fused2_kernel<<<(N_NODES + 255) / 256, 256, 0, stream>>>(row_ptr, csr_src, h2, norm_dst, b2, out);
}

// Round 3
// 229.246 us; speedup vs baseline: 2.1173x; 1.3746x over previous
//
#include <hip/hip_runtime.h>
#include <math.h>

#define N_NODES 50000
#define N_EDGES 800000
#define NFEAT 256
#define NHID 64
#define NCLASS 2

#define EPB 4096                       // edges per scatter/hist block (16/thread)
#define NB_EDGE ((N_EDGES + EPB - 1) / EPB)  // 196

// ---------------- workspace layout (4-byte units) ----------------
#define OFF_HISTD  0        // int[256]  coarse hist of dst>>8
#define OFF_HISTS  256      // int[256]  coarse hist of src>>8
#define OFF_BASED  512      // int[257]  exclusive scan (dst buckets)
#define OFF_BASES  772      // int[257]  exclusive scan (src buckets)
#define OFF_CURD   1036     // int[256]  global cursors (dst)
#define OFF_CURS   1292     // int[256]  global cursors (src)
#define OFF_RP     1548     // int[50001] CSR row_ptr (by dst)
#define OFF_NDST   51552    // f32[50000]
#define OFF_NSRC   101552   // f32[50000]
#define OFF_DPAIRS 151552   // int2[800000] (src, dst&255) partitioned by dst>>8
#define OFF_SVALS  1751552  // int[800000]  src&255 partitioned by src>>8
#define OFF_H      2551552  // f32[3200000] h = (x*norm_src)@W1
#define OFF_H2     5751552  // f32[100000]

// K1: coarse 256-bucket histograms of dst>>8 and src>>8 (LDS, tiny global flush)
__global__ __launch_bounds__(256) void bhist_kernel(const int* __restrict__ src,
                                                    const int* __restrict__ dst,
                                                    int* __restrict__ hist_d,
                                                    int* __restrict__ hist_s) {
    __shared__ int hd[256], hs[256];
    int t = threadIdx.x;
    hd[t] = 0; hs[t] = 0;
    __syncthreads();
    int base = blockIdx.x * EPB;
#pragma unroll
    for (int i = 0; i < 16; ++i) {
        int e = base + t + i * 256;
        if (e < N_EDGES) {
            atomicAdd(&hd[dst[e] >> 8], 1);
            atomicAdd(&hs[src[e] >> 8], 1);
        }
    }
    __syncthreads();
    if (hd[t]) atomicAdd(&hist_d[t], hd[t]);
    if (hs[t]) atomicAdd(&hist_s[t], hs[t]);
}

// K2: exclusive scans of both coarse hists -> bucket bases + cursors; sentinel
__global__ void bscan_kernel(const int* __restrict__ hist_d, const int* __restrict__ hist_s,
                             int* __restrict__ base_d, int* __restrict__ base_s,
                             int* __restrict__ cur_d, int* __restrict__ cur_s,
                             int* __restrict__ row_ptr) {
    __shared__ int s[256];
    int t = threadIdx.x;
    int v = hist_d[t];
    s[t] = v;
    __syncthreads();
#pragma unroll
    for (int off = 1; off < 256; off <<= 1) {
        int x = (t >= off) ? s[t - off] : 0;
        __syncthreads();
        s[t] += x;
        __syncthreads();
    }
    base_d[t] = s[t] - v;
    cur_d[t] = s[t] - v;
    if (t == 255) base_d[256] = s[255];
    __syncthreads();
    int w = hist_s[t];
    s[t] = w;
    __syncthreads();
#pragma unroll
    for (int off = 1; off < 256; off <<= 1) {
        int x = (t >= off) ? s[t - off] : 0;
        __syncthreads();
        s[t] += x;
        __syncthreads();
    }
    base_s[t] = s[t] - w;
    cur_s[t] = s[t] - w;
    if (t == 255) base_s[256] = s[255];
    if (t == 0) row_ptr[N_NODES] = N_EDGES;
}

// K3: partition edges into dst-buckets (as (src, dst&255) pairs) and src-buckets
// (as src&255). Per-block LDS hist -> ONE global atomic per touched bucket.
__global__ __launch_bounds__(256) void bscatter_kernel(const int* __restrict__ src,
                                                       const int* __restrict__ dst,
                                                       int* __restrict__ cur_d,
                                                       int* __restrict__ cur_s,
                                                       int2* __restrict__ dpairs,
                                                       int* __restrict__ svals) {
    __shared__ int hd[256], hs[256], bd[256], bs[256], cd[256], cs[256];
    int t = threadIdx.x;
    hd[t] = 0; hs[t] = 0; cd[t] = 0; cs[t] = 0;
    __syncthreads();
    int base = blockIdx.x * EPB;
    int ls[16], ld[16];
#pragma unroll
    for (int i = 0; i < 16; ++i) {
        int e = base + t + i * 256;
        ls[i] = (e < N_EDGES) ? src[e] : -1;
        ld[i] = (e < N_EDGES) ? dst[e] : -1;
        if (ld[i] >= 0) {
            atomicAdd(&hd[ld[i] >> 8], 1);
            atomicAdd(&hs[ls[i] >> 8], 1);
        }
    }
    __syncthreads();
    if (hd[t]) bd[t] = atomicAdd(&cur_d[t], hd[t]);
    if (hs[t]) bs[t] = atomicAdd(&cur_s[t], hs[t]);
    __syncthreads();
#pragma unroll
    for (int i = 0; i < 16; ++i) {
        if (ld[i] >= 0) {
            int bin = ld[i] >> 8;
            int pos = bd[bin] + atomicAdd(&cd[bin], 1);
            dpairs[pos] = make_int2(ls[i], ld[i] & 255);
            int sbin = ls[i] >> 8;
            int spos = bs[sbin] + atomicAdd(&cs[sbin], 1);
            svals[spos] = ls[i] & 255;
        }
    }
}

// K4: per dst-bucket: exact in-degrees (256-bin LDS hist) -> norm_dst + row_ptr,
// then rank edges via LDS cursors -> csr_src. No global atomics.
__global__ __launch_bounds__(256) void dfin_kernel(const int* __restrict__ base_d,
                                                   const int2* __restrict__ dpairs,
                                                   int* __restrict__ row_ptr,
                                                   float* __restrict__ norm_dst,
                                                   int* __restrict__ csr_src) {
    __shared__ int hist[256], seg[256], cur[256];
    int b = blockIdx.x, t = threadIdx.x;
    int beg = base_d[b], end = base_d[b + 1];
    hist[t] = 0; cur[t] = 0;
    __syncthreads();
    for (int j = beg + t; j < end; j += 256) atomicAdd(&hist[dpairs[j].y], 1);
    __syncthreads();
    int v = hist[t];
    seg[t] = v;
    __syncthreads();
#pragma unroll
    for (int off = 1; off < 256; off <<= 1) {
        int x = (t >= off) ? seg[t - off] : 0;
        __syncthreads();
        seg[t] += x;
        __syncthreads();
    }
    int excl = seg[t] - v;
    int gid = b * 256 + t;
    if (gid < N_NODES) {
        row_ptr[gid] = beg + excl;
        norm_dst[gid] = rsqrtf(fmaxf((float)v, 1.0f));
    }
    seg[t] = excl;
    __syncthreads();
    for (int j = beg + t; j < end; j += 256) {
        int2 p = dpairs[j];
        int pos = beg + seg[p.y] + atomicAdd(&cur[p.y], 1);
        csr_src[pos] = p.x;
    }
}

// K5: per src-bucket: exact out-degrees -> norm_src
__global__ __launch_bounds__(256) void sfin_kernel(const int* __restrict__ base_s,
                                                   const int* __restrict__ svals,
                                                   float* __restrict__ norm_src) {
    __shared__ int hist[256];
    int b = blockIdx.x, t = threadIdx.x;
    hist[t] = 0;
    __syncthreads();
    int beg = base_s[b], end = base_s[b + 1];
    for (int j = beg + t; j < end; j += 256) atomicAdd(&hist[svals[j]], 1);
    __syncthreads();
    int gid = b * 256 + t;
    if (gid < N_NODES) norm_src[gid] = rsqrtf(fmaxf((float)hist[t], 1.0f));
}

// h[50000x64] = (x * norm_src[:,None]) @ W1[256x64]
#define BM 64
#define BK 16
__global__ __launch_bounds__(256) void gemm1_kernel(const float* __restrict__ x,
                                                    const float* __restrict__ W1,
                                                    const float* __restrict__ norm_src,
                                                    float* __restrict__ h) {
    __shared__ float As[BK][BM + 4];
    __shared__ float Bs[BK][NHID + 4];
    const int row0 = blockIdx.x * BM;
    const int t = threadIdx.x;
    const int tx = t & 15;
    const int ty = t >> 4;
    const int ar = t >> 2;
    const int ak = (t & 3) * 4;
    const int bk = t >> 4;
    const int bc = (t & 15) * 4;
    const int grow = row0 + ar;
    const float anorm = (grow < N_NODES) ? norm_src[grow] : 0.0f;

    float acc[4][4] = {};
    for (int k0 = 0; k0 < NFEAT; k0 += BK) {
        float4 av = make_float4(0.f, 0.f, 0.f, 0.f);
        if (grow < N_NODES) av = *(const float4*)(&x[grow * NFEAT + k0 + ak]);
        As[ak + 0][ar] = av.x * anorm;
        As[ak + 1][ar] = av.y * anorm;
        As[ak + 2][ar] = av.z * anorm;
        As[ak + 3][ar] = av.w * anorm;
        *(float4*)(&Bs[bk][bc]) = *(const float4*)(&W1[(k0 + bk) * NHID + bc]);
        __syncthreads();
#pragma unroll
        for (int kk = 0; kk < BK; ++kk) {
            float4 a4 = *(const float4*)(&As[kk][ty * 4]);
            float4 b4 = *(const float4*)(&Bs[kk][tx * 4]);
            float a[4] = {a4.x, a4.y, a4.z, a4.w};
            float b[4] = {b4.x, b4.y, b4.z, b4.w};
#pragma unroll
            for (int i = 0; i < 4; ++i)
#pragma unroll
                for (int j = 0; j < 4; ++j)
                    acc[i][j] = fmaf(a[i], b[j], acc[i][j]);
        }
        __syncthreads();
    }
#pragma unroll
    for (int i = 0; i < 4; ++i) {
        int r = row0 + ty * 4 + i;
        if (r < N_NODES) {
            float4 o = make_float4(acc[i][0], acc[i][1], acc[i][2], acc[i][3]);
            *(float4*)(&h[r * NHID + tx * 4]) = o;
        }
    }
}

// Fused layer1 per dst node (one wave, lane = feature): agg over CSR ->
// relu(agg*norm_dst+b1) -> *norm_src -> @W2 -> h2[n][0:2]
__global__ void fused1_kernel(const int* __restrict__ row_ptr, const int* __restrict__ csr_src,
                              const float* __restrict__ h, const float* __restrict__ norm_dst,
                              const float* __restrict__ norm_src, const float* __restrict__ b1,
                              const float* __restrict__ W2, float* __restrict__ h2) {
    int gtid = blockIdx.x * blockDim.x + threadIdx.x;
    int node = gtid >> 6;
    int lane = gtid & 63;
    if (node >= N_NODES) return;
    int beg = row_ptr[node], end = row_ptr[node + 1];
    float acc0 = 0.f, acc1 = 0.f;
    int j = beg;
    for (; j + 1 < end; j += 2) {
        int s0 = csr_src[j], s1 = csr_src[j + 1];
        acc0 += h[s0 * 64 + lane];
        acc1 += h[s1 * 64 + lane];
    }
    if (j < end) acc0 += h[csr_src[j] * 64 + lane];
    float agg = acc0 + acc1;
    float h1 = fmaxf(fmaf(agg, norm_dst[node], b1[lane]), 0.0f);
    float hv = h1 * norm_src[node];
    float p0 = hv * W2[lane * 2 + 0];
    float p1 = hv * W2[lane * 2 + 1];
#pragma unroll
    for (int off = 32; off > 0; off >>= 1) {
        p0 += __shfl_xor(p0, off, 64);
        p1 += __shfl_xor(p1, off, 64);
    }
    if (lane == 0) *(float2*)(&h2[node * 2]) = make_float2(p0, p1);
}

// Fused layer2 per dst node (one thread): agg h2 -> logits -> log_softmax
__global__ void fused2_kernel(const int* __restrict__ row_ptr, const int* __restrict__ csr_src,
                              const float* __restrict__ h2, const float* __restrict__ norm_dst,
                              const float* __restrict__ b2, float* __restrict__ out) {
    int n = blockIdx.x * blockDim.x + threadIdx.x;
    if (n >= N_NODES) return;
    int beg = row_ptr[n], end = row_ptr[n + 1];
    float s0 = 0.f, s1 = 0.f;
    for (int j = beg; j < end; ++j) {
        float2 v = *(const float2*)(&h2[csr_src[j] * 2]);
        s0 += v.x;
        s1 += v.y;
    }
    float nd = norm_dst[n];
    float l0 = fmaf(s0, nd, b2[0]);
    float l1 = fmaf(s1, nd, b2[1]);
    float m = fmaxf(l0, l1);
    float lse = m + logf(expf(l0 - m) + expf(l1 - m));
    *(float2*)(&out[n * 2]) = make_float2(l0 - lse, l1 - lse);
}

extern "C" void kernel_launch(void* const* d_in, const int* in_sizes, int n_in,
                              void* d_out, int out_size, void* d_ws, size_t ws_size,
                              hipStream_t stream) {
    const float* x  = (const float*)d_in[0];
    const int* src  = (const int*)d_in[1];
    const int* dst  = (const int*)d_in[2];
    const float* W1 = (const float*)d_in[3];
    const float* b1 = (const float*)d_in[4];
    const float* W2 = (const float*)d_in[5];
    const float* b2 = (const float*)d_in[6];
    float* out = (float*)d_out;
    float* ws  = (float*)d_ws;
    int*   wsi = (int*)d_ws;

    int*   hist_d   = wsi + OFF_HISTD;
    int*   hist_s   = wsi + OFF_HISTS;
    int*   base_d   = wsi + OFF_BASED;
    int*   base_s   = wsi + OFF_BASES;
    int*   cur_d    = wsi + OFF_CURD;
    int*   cur_s    = wsi + OFF_CURS;
    int*   row_ptr  = wsi + OFF_RP;
    float* norm_dst = ws + OFF_NDST;
    float* norm_src = ws + OFF_NSRC;
    int2*  dpairs   = (int2*)(wsi + OFF_DPAIRS);
    int*   svals    = wsi + OFF_SVALS;
    int*   csr_src  = wsi + OFF_SVALS;  // reuse svals region AFTER sfin? NO — overlap hazard.
    float* h        = ws + OFF_H;
    float* h2       = ws + OFF_H2;

    // csr_src must not alias svals (dfin and sfin order not enforced between
    // them on different data). Reuse the dpairs region is also unsafe (dfin
    // reads it while writing csr). Keep csr in dpairs' second half? dpairs is
    // int2[800000]; csr needs int[800000]. dfin reads dpairs[j] and writes
    // csr[pos] with pos in the same bucket range — overlapping reads/writes
    // within the same kernel = hazard. So place csr after H2 instead.
    csr_src = wsi + (OFF_H2 + 100000);  // int[800000], ends at 6651552 (26.6 MB)

    hipMemsetAsync(hist_d, 0, 512 * sizeof(int), stream);
    bhist_kernel<<<NB_EDGE, 256, 0, stream>>>(src, dst, hist_d, hist_s);
    bscan_kernel<<<1, 256, 0, stream>>>(hist_d, hist_s, base_d, base_s, cur_d, cur_s, row_ptr);
    bscatter_kernel<<<NB_EDGE, 256, 0, stream>>>(src, dst, cur_d, cur_s, dpairs, svals);
    dfin_kernel<<<256, 256, 0, stream>>>(base_d, dpairs, row_ptr, norm_dst, csr_src);
    sfin_kernel<<<256, 256, 0, stream>>>(base_s, svals, norm_src);
    gemm1_kernel<<<(N_NODES + BM - 1) / BM, 256, 0, stream>>>(x, W1, norm_src, h);
    {
        long long threads = (long long)N_NODES * 64;
        fused1_kernel<<<(int)((threads + 255) / 256), 256, 0, stream>>>(
            row_ptr, csr_src, h, norm_dst, norm_src, b1, W2, h2);
    }
    fused2_kernel<<<(N_NODES + 255) / 256, 256, 0, stream>>>(row_ptr, csr_src, h2, norm_dst, b2, out);
}

// Round 4
// 207.766 us; speedup vs baseline: 2.3362x; 1.1034x over previous
//
#include <hip/hip_runtime.h>
#include <math.h>

#define N_NODES 50000
#define N_EDGES 800000
#define NFEAT 256
#define NHID 64
#define NCLASS 2

#define NBUCK 196        // buckets = node>>8, 50000>>8 = 195
#define BCAP 8192        // fixed bucket capacity (mean 4081, sigma 64 -> +64 sigma)
#define EPB 4096         // edges per scatter block (16/thread)
#define NB_EDGE ((N_EDGES + EPB - 1) / EPB)  // 196

// ---------------- workspace layout (4-byte units) ----------------
#define OFF_CURD 0        // int[256]  dst-bucket cursors (memset 0)
#define OFF_CURS 256      // int[256]  src-bucket cursors (memset 0)
#define OFF_RB   512      // int[50000] row_beg (into fixed-stride csr)
#define OFF_DEG  50512    // int[50000] in-degree
#define OFF_NDST 100512   // f32[50000]
#define OFF_NSRC 150512   // f32[50000]
#define OFF_DPK  200512   // int[196*8192] packed (src<<8|dst&255) by dst>>8
#define OFF_SV8  1806144  // uchar[196*8192] (src&255) by src>>8  (401408 words)
#define OFF_CSR  2207552  // int[196*8192] csr src ids (fixed stride)
#define OFF_HB   3813184  // bf16[50000*64] = 1600000 words
#define OFF_H2   5413184  // f32[100000]

typedef __attribute__((ext_vector_type(8))) short bf16x8;
typedef __attribute__((ext_vector_type(4))) float f32x4;

static __device__ __forceinline__ unsigned short f2bf(float f) {
    union { float f; unsigned int u; } v; v.f = f;
    unsigned int u = v.u + 0x7fffu + ((v.u >> 16) & 1u);  // RNE
    return (unsigned short)(u >> 16);
}
static __device__ __forceinline__ float bf2f(unsigned int hi16) {
    union { unsigned int u; float f; } v; v.u = hi16 << 16;
    return v.f;
}

// K1: partition edges into fixed-capacity dst-buckets (packed src|dstlow) and
// src-buckets (src&255 bytes). Per-block LDS hist -> one global atomic per
// touched bucket -> LDS-ranked scatter.
__global__ __launch_bounds__(256) void bscatter_kernel(const int* __restrict__ src,
                                                       const int* __restrict__ dst,
                                                       int* __restrict__ cur_d,
                                                       int* __restrict__ cur_s,
                                                       int* __restrict__ dpk,
                                                       unsigned char* __restrict__ sv8) {
    __shared__ int hd[256], hs[256], bd[256], bs[256], cd[256], cs[256];
    int t = threadIdx.x;
    hd[t] = 0; hs[t] = 0; cd[t] = 0; cs[t] = 0;
    __syncthreads();
    int base = blockIdx.x * EPB;
    int ls[16], ld[16];
#pragma unroll
    for (int i = 0; i < 16; ++i) {
        int e = base + t + i * 256;
        ls[i] = (e < N_EDGES) ? src[e] : -1;
        ld[i] = (e < N_EDGES) ? dst[e] : -1;
        if (ld[i] >= 0) {
            atomicAdd(&hd[ld[i] >> 8], 1);
            atomicAdd(&hs[ls[i] >> 8], 1);
        }
    }
    __syncthreads();
    if (hd[t]) bd[t] = atomicAdd(&cur_d[t], hd[t]);
    if (hs[t]) bs[t] = atomicAdd(&cur_s[t], hs[t]);
    __syncthreads();
#pragma unroll
    for (int i = 0; i < 16; ++i) {
        if (ld[i] >= 0) {
            int bin = ld[i] >> 8;
            int pos = bd[bin] + atomicAdd(&cd[bin], 1);
            dpk[bin * BCAP + pos] = (ls[i] << 8) | (ld[i] & 255);
            int sbin = ls[i] >> 8;
            int spos = bs[sbin] + atomicAdd(&cs[sbin], 1);
            sv8[sbin * BCAP + spos] = (unsigned char)(ls[i] & 255);
        }
    }
}

// K2: per dst-bucket: in-degree hist -> row_beg/deg/norm_dst; rank -> csr
__global__ __launch_bounds__(256) void dfin_kernel(const int* __restrict__ cur_d,
                                                   const int* __restrict__ dpk,
                                                   int* __restrict__ row_beg,
                                                   int* __restrict__ degv,
                                                   float* __restrict__ norm_dst,
                                                   int* __restrict__ csr) {
    __shared__ int hist[256], seg[256], cur[256];
    int b = blockIdx.x, t = threadIdx.x;
    int cnt = cur_d[b];
    int base = b * BCAP;
    hist[t] = 0; cur[t] = 0;
    __syncthreads();
    for (int j = t; j < cnt; j += 256) atomicAdd(&hist[dpk[base + j] & 255], 1);
    __syncthreads();
    int v = hist[t];
    seg[t] = v;
    __syncthreads();
#pragma unroll
    for (int off = 1; off < 256; off <<= 1) {
        int x = (t >= off) ? seg[t - off] : 0;
        __syncthreads();
        seg[t] += x;
        __syncthreads();
    }
    int excl = seg[t] - v;
    int gid = b * 256 + t;
    if (gid < N_NODES) {
        row_beg[gid] = base + excl;
        degv[gid] = v;
        norm_dst[gid] = rsqrtf(fmaxf((float)v, 1.0f));
    }
    seg[t] = excl;
    __syncthreads();
    for (int j = t; j < cnt; j += 256) {
        int p = dpk[base + j];
        int dlow = p & 255;
        int pos = base + seg[dlow] + atomicAdd(&cur[dlow], 1);
        csr[pos] = ((unsigned)p) >> 8;
    }
}

// K3: per src-bucket: out-degree hist -> norm_src
__global__ __launch_bounds__(256) void sfin_kernel(const int* __restrict__ cur_s,
                                                   const unsigned char* __restrict__ sv8,
                                                   float* __restrict__ norm_src) {
    __shared__ int hist[256];
    int b = blockIdx.x, t = threadIdx.x;
    hist[t] = 0;
    __syncthreads();
    int cnt = cur_s[b];
    int base = b * BCAP;
    for (int j = t; j < cnt; j += 256) atomicAdd(&hist[sv8[base + j]], 1);
    __syncthreads();
    int gid = b * 256 + t;
    if (gid < N_NODES) norm_src[gid] = rsqrtf(fmaxf((float)hist[t], 1.0f));
}

// K4: h_bf16[50000x64] = bf16( (x * norm_src[:,None]) @ W1[256x64] )
// 64-row x 64-col tile per block (4 waves x 16 rows), full K=256 in LDS, MFMA.
#define LDA 264  // padded bf16 row stride (132 dwords -> 2-way max on frag reads)
__global__ __launch_bounds__(256) void gemm1_kernel(const float* __restrict__ x,
                                                    const float* __restrict__ W1,
                                                    const float* __restrict__ norm_src,
                                                    unsigned short* __restrict__ hb) {
    __shared__ unsigned short As[64][LDA];  // As[row][k]
    __shared__ unsigned short Bs[64][LDA];  // Bs[n][k]   (W1 transposed)
    const int t = threadIdx.x;
    const int row0 = blockIdx.x * 64;
    // ---- stage A: 64x256 fp32 -> *norm -> bf16 ----
#pragma unroll
    for (int i = 0; i < 16; ++i) {
        int f = i * 256 + t;          // float4 index in tile
        int r = f >> 6;
        int c4 = (f & 63) * 4;
        int grow = row0 + r;
        float4 av = make_float4(0.f, 0.f, 0.f, 0.f);
        float nrm = 0.f;
        if (grow < N_NODES) {
            av = *(const float4*)(&x[(size_t)grow * NFEAT + c4]);
            nrm = norm_src[grow];
        }
        ushort4 o;
        o.x = f2bf(av.x * nrm); o.y = f2bf(av.y * nrm);
        o.z = f2bf(av.z * nrm); o.w = f2bf(av.w * nrm);
        *(ushort4*)(&As[r][c4]) = o;
    }
    // ---- stage B: W1[k][n] fp32 -> bf16 transposed Bs[n][k] ----
#pragma unroll
    for (int i = 0; i < 16; ++i) {
        int f = i * 256 + t;          // float4 index in 256x16(float4) grid
        int k = f >> 4;
        int n4 = (f & 15) * 4;
        float4 wv = *(const float4*)(&W1[k * NHID + n4]);
        Bs[n4 + 0][k] = f2bf(wv.x);
        Bs[n4 + 1][k] = f2bf(wv.y);
        Bs[n4 + 2][k] = f2bf(wv.z);
        Bs[n4 + 3][k] = f2bf(wv.w);
    }
    __syncthreads();
    // ---- MFMA: wave w -> rows [w*16, w*16+16), 4 col-tiles of 16 ----
    const int w = t >> 6;
    const int l = t & 63;
    const int m = l & 15;
    const int kq = (l >> 4) * 8;
    f32x4 acc[4] = {{0.f, 0.f, 0.f, 0.f}, {0.f, 0.f, 0.f, 0.f},
                    {0.f, 0.f, 0.f, 0.f}, {0.f, 0.f, 0.f, 0.f}};
#pragma unroll
    for (int c8 = 0; c8 < 8; ++c8) {
        int k0 = c8 * 32 + kq;
        bf16x8 a = *(const bf16x8*)(&As[w * 16 + m][k0]);
#pragma unroll
        for (int ct = 0; ct < 4; ++ct) {
            bf16x8 b = *(const bf16x8*)(&Bs[ct * 16 + m][k0]);
            acc[ct] = __builtin_amdgcn_mfma_f32_16x16x32_bf16(a, b, acc[ct], 0, 0, 0);
        }
    }
    // ---- epilogue: C/D map col=lane&15, row=(lane>>4)*4+reg ----
    const int q = l >> 4;
#pragma unroll
    for (int ct = 0; ct < 4; ++ct) {
#pragma unroll
        for (int reg = 0; reg < 4; ++reg) {
            int r = row0 + w * 16 + q * 4 + reg;
            if (r < N_NODES) hb[(size_t)r * NHID + ct * 16 + m] = f2bf(acc[ct][reg]);
        }
    }
}

// K5: fused layer1 per dst node (one wave; half-wave = one edge, lane pair = 2 feats):
//   agg = sum csr h_bf16 rows; h1 = relu(agg*nd + b1); hv = h1*ns; h2 = hv @ W2
__global__ void fused1_kernel(const int* __restrict__ row_beg, const int* __restrict__ degv,
                              const int* __restrict__ csr, const unsigned short* __restrict__ hb,
                              const float* __restrict__ norm_dst, const float* __restrict__ norm_src,
                              const float* __restrict__ b1, const float* __restrict__ W2,
                              float* __restrict__ h2) {
    int gtid = blockIdx.x * blockDim.x + threadIdx.x;
    int node = gtid >> 6;
    int lane = gtid & 63;
    if (node >= N_NODES) return;
    int p = lane & 31;       // feature pair index
    int half = lane >> 5;    // which edge of the pair
    int beg = row_beg[node];
    int end = beg + degv[node];
    float ax = 0.f, ay = 0.f;
    for (int j = beg + half; j < end; j += 2) {
        int s = csr[j];
        unsigned int u = *(const unsigned int*)(&hb[(size_t)s * NHID + p * 2]);
        ax += bf2f(u & 0xffffu);
        ay += bf2f(u >> 16);
    }
    ax += __shfl_xor(ax, 32, 64);
    ay += __shfl_xor(ay, 32, 64);
    float nd = norm_dst[node], ns = norm_src[node];
    float2 bv = *(const float2*)(&b1[p * 2]);
    float h1a = fmaxf(fmaf(ax, nd, bv.x), 0.0f) * ns;
    float h1b = fmaxf(fmaf(ay, nd, bv.y), 0.0f) * ns;
    float4 wv = *(const float4*)(&W2[p * 4]);  // feats 2p,2p+1 x classes 0,1
    float p0 = fmaf(h1a, wv.x, h1b * wv.z);
    float p1 = fmaf(h1a, wv.y, h1b * wv.w);
#pragma unroll
    for (int off = 16; off > 0; off >>= 1) {
        p0 += __shfl_xor(p0, off, 64);
        p1 += __shfl_xor(p1, off, 64);
    }
    if (lane == 0) *(float2*)(&h2[node * 2]) = make_float2(p0, p1);
}

// K6: fused layer2 per dst node: agg h2 -> logits -> log_softmax
__global__ void fused2_kernel(const int* __restrict__ row_beg, const int* __restrict__ degv,
                              const int* __restrict__ csr, const float* __restrict__ h2,
                              const float* __restrict__ norm_dst, const float* __restrict__ b2,
                              float* __restrict__ out) {
    int n = blockIdx.x * blockDim.x + threadIdx.x;
    if (n >= N_NODES) return;
    int beg = row_beg[n], end = beg + degv[n];
    float s0 = 0.f, s1 = 0.f;
    for (int j = beg; j < end; ++j) {
        float2 v = *(const float2*)(&h2[csr[j] * 2]);
        s0 += v.x;
        s1 += v.y;
    }
    float nd = norm_dst[n];
    float l0 = fmaf(s0, nd, b2[0]);
    float l1 = fmaf(s1, nd, b2[1]);
    float m = fmaxf(l0, l1);
    float lse = m + logf(expf(l0 - m) + expf(l1 - m));
    *(float2*)(&out[n * 2]) = make_float2(l0 - lse, l1 - lse);
}

extern "C" void kernel_launch(void* const* d_in, const int* in_sizes, int n_in,
                              void* d_out, int out_size, void* d_ws, size_t ws_size,
                              hipStream_t stream) {
    const float* x  = (const float*)d_in[0];
    const int* src  = (const int*)d_in[1];
    const int* dst  = (const int*)d_in[2];
    const float* W1 = (const float*)d_in[3];
    const float* b1 = (const float*)d_in[4];
    const float* W2 = (const float*)d_in[5];
    const float* b2 = (const float*)d_in[6];
    float* out = (float*)d_out;
    float* ws  = (float*)d_ws;
    int*   wsi = (int*)d_ws;

    int*   cur_d    = wsi + OFF_CURD;
    int*   cur_s    = wsi + OFF_CURS;
    int*   row_beg  = wsi + OFF_RB;
    int*   degv     = wsi + OFF_DEG;
    float* norm_dst = ws + OFF_NDST;
    float* norm_src = ws + OFF_NSRC;
    int*   dpk      = wsi + OFF_DPK;
    unsigned char* sv8 = (unsigned char*)(wsi + OFF_SV8);
    int*   csr      = wsi + OFF_CSR;
    unsigned short* hb = (unsigned short*)(wsi + OFF_HB);
    float* h2       = ws + OFF_H2;

    hipMemsetAsync(cur_d, 0, 512 * sizeof(int), stream);
    bscatter_kernel<<<NB_EDGE, 256, 0, stream>>>(src, dst, cur_d, cur_s, dpk, sv8);
    dfin_kernel<<<NBUCK, 256, 0, stream>>>(cur_d, dpk, row_beg, degv, norm_dst, csr);
    sfin_kernel<<<NBUCK, 256, 0, stream>>>(cur_s, sv8, norm_src);
    gemm1_kernel<<<(N_NODES + 63) / 64, 256, 0, stream>>>(x, W1, norm_src, hb);
    {
        long long threads = (long long)N_NODES * 64;
        fused1_kernel<<<(int)((threads + 255) / 256), 256, 0, stream>>>(
            row_beg, degv, csr, hb, norm_dst, norm_src, b1, W2, h2);
    }
    fused2_kernel<<<(N_NODES + 255) / 256, 256, 0, stream>>>(row_beg, degv, csr, h2, norm_dst, b2, out);
}